// Round 15
// baseline (493.279 us; speedup 1.0000x reference)
//
#include <hip/hip_runtime.h>
#include <hip/hip_bf16.h>

typedef __hip_bfloat16 bf16;
typedef unsigned short ushortT;
typedef unsigned int uintT;
typedef __attribute__((ext_vector_type(8))) short bf16x8;
typedef __attribute__((ext_vector_type(4))) float f32x4;

#define D 128
#define NLEV 5
#define TE 16  // edges per tile (MFMA M=16)
#define TN 16  // nodes per tile
#define EGRID 2048  // grid-stride edge kernel

// weight blob element offsets (bf16 elements), all stored transposed [C][K]
#define OFF_S1 0          // [5][128][128]
#define OFF_S2 81920      // [5][128][128]
#define OFF_F1 163840     // [4][128][256]
#define OFF_F2 294912     // [4][128][128]
#define OFF_NF1 360448    // [128][128]
#define OFF_NF2 376832    // [128][128]
#define OFF_GSH 393216    // [5][384][128] Gs_wih hi
#define OFF_GFH 638976    // [5][384][128] Gf_wih hi
#define OFF_GSL 884736    // [5][384][128] Gs_wih lo
#define OFF_GFL 1130496   // [5][384][128] Gf_wih lo
#define WT_TOTAL 1376256

// gate code -> t (enumerate index in CODES=[3,2,5,1,4]); index 0 unused
__constant__ int TMAP[6] = { -1, 3, 1, 0, 4, 2 };
// gate code -> func-aggregator index (FIDX={3:0,5:1,1:2,4:3}); codes 0,2 unused
__constant__ int FMAP[6] = { -1, 2, -1, 0, 3, 1 };

// dtype flag: 1 = float tensors stored as bf16, 0 = stored as float32
__device__ int g_flag;

__device__ __forceinline__ float sigm(float x) { return 1.0f / (1.0f + __expf(-x)); }

__device__ __forceinline__ ushortT f2b(float v) {
    bf16 h = __float2bfloat16(v);
    return *reinterpret_cast<ushortT*>(&h);
}

template <int ISB>
__device__ __forceinline__ float ld(const void* p, size_t i) {
    if (ISB) return __bfloat162float(((const bf16*)p)[i]);
    return ((const float*)p)[i];
}

__device__ __forceinline__ float ldx(int isb, const void* p, size_t i) {
    return isb ? __bfloat162float(((const bf16*)p)[i]) : ((const float*)p)[i];
}

// ===== fused setup: role-partitioned blocks =====
// roles: [0,B_init): state-init + agg-zero (8 nodes/block, 4 elems/thread)
//        [B_init,B_init+B_cnt): count_bins
//        [B_init+B_cnt, ...): prep_weights
__global__ __launch_bounds__(256) void setup_a(
    const void* __restrict__ hs_init, const int* __restrict__ gate,
    const int* __restrict__ dstA, const int* __restrict__ lev,
    int E, int N, int ND,
    ushortT* __restrict__ hsb, ushortT* __restrict__ hfb, void* __restrict__ out,
    float* __restrict__ agg_s, float* __restrict__ agg_f,
    int* __restrict__ ecnt, int* __restrict__ ncnt, int* __restrict__ ndeg,
    const void* Ws1, const void* Ws2, const void* Wf1, const void* Wf2,
    const void* Wnf1, const void* Wnf2, const void* Gs, const void* Gf,
    ushortT* __restrict__ wt, int B_init, int B_cnt) {
    __shared__ int sfl;
    __shared__ int lc[40];
    int tid = threadIdx.x;
    int bid = blockIdx.x;

    if (tid < 64) {
        float x = __bfloat162float(((const bf16*)hs_init)[2 * tid]);
        float ax = fabsf(x);
        bool sane = (x == 0.0f) || (ax > 1e-4f && ax < 64.0f);
        unsigned long long m = __ballot(sane);
        if (tid == 0) sfl = (__popcll(m) >= 32) ? 1 : 0;
    }
    __syncthreads();
    int isb = sfl;
    if (bid == 0 && tid == 0) g_flag = isb;

    if (bid < B_init) {
        // ---- init role: 8 nodes/block; each thread handles 4 consecutive j ----
        int v = (bid << 3) | (tid >> 5);
        int j = (tid & 31) * 4;
        if (v < N) {
            size_t idx = (size_t)v * D + j;
            bool pi = (gate[v] == 0);
            if (isb) {
                uint2 bv = make_uint2(0u, 0u);
                if (pi) bv = *(const uint2*)((const ushortT*)hs_init + idx);
                *(uint2*)&hsb[idx] = bv;
                *(uint2*)&hfb[idx] = make_uint2(0u, 0u);
                *(uint2*)&((ushortT*)out)[idx] = bv;
                *(uint2*)&((ushortT*)out)[ND + idx] = make_uint2(0u, 0u);
            } else {
                float4 fv = make_float4(0.f, 0.f, 0.f, 0.f);
                if (pi) fv = *(const float4*)((const float*)hs_init + idx);
                ushortT b0 = f2b(fv.x), b1 = f2b(fv.y), b2 = f2b(fv.z), b3 = f2b(fv.w);
                *(uint2*)&hsb[idx] = make_uint2((uintT)b0 | ((uintT)b1 << 16),
                                                (uintT)b2 | ((uintT)b3 << 16));
                *(uint2*)&hfb[idx] = make_uint2(0u, 0u);
                *(float4*)&((float*)out)[idx] = fv;
                *(float4*)&((float*)out)[ND + idx] = make_float4(0.f, 0.f, 0.f, 0.f);
            }
            *(float4*)&agg_s[idx] = make_float4(0.f, 0.f, 0.f, 0.f);
            *(float4*)&agg_f[idx] = make_float4(0.f, 0.f, 0.f, 0.f);
        }
    } else if (bid < B_init + B_cnt) {
        // ---- count role ----
        if (tid < 40) lc[tid] = 0;
        __syncthreads();
        int i = (bid - B_init) * 256 + tid;
        if (i < E) {
            int d = dstA[i]; int l = lev[d];
            if (l >= 1 && l < NLEV) {
                atomicAdd(&lc[(l - 1) * 5 + TMAP[gate[d]]], 1);
                atomicAdd(&ndeg[d], 1);
            }
        }
        if (i < N) {
            int l = lev[i];
            if (l >= 1 && l < NLEV && gate[i] >= 1)
                atomicAdd(&lc[20 + (l - 1) * 5 + TMAP[gate[i]]], 1);
        }
        __syncthreads();
        if (tid < 20 && lc[tid]) atomicAdd(&ecnt[tid], lc[tid]);
        if (tid >= 20 && tid < 40 && lc[tid]) atomicAdd(&ncnt[tid - 20], lc[tid]);
    } else {
        // ---- weight-prep role ----
        int i = (bid - B_init - B_cnt) * 256 + tid;
        if (i >= WT_TOTAL) return;
        const void* src; int Kd, C, rem, mode = 0;  // 0: plain, 1: hi, 2: lo
        if (i < OFF_S2)       { src = Ws1;  rem = i;           Kd = 128; C = 128; }
        else if (i < OFF_F1)  { src = Ws2;  rem = i - OFF_S2;  Kd = 128; C = 128; }
        else if (i < OFF_F2)  { src = Wf1;  rem = i - OFF_F1;  Kd = 256; C = 128; }
        else if (i < OFF_NF1) { src = Wf2;  rem = i - OFF_F2;  Kd = 128; C = 128; }
        else if (i < OFF_NF2) { src = Wnf1; rem = i - OFF_NF1; Kd = 128; C = 128; }
        else if (i < OFF_GSH) { src = Wnf2; rem = i - OFF_NF2; Kd = 128; C = 128; }
        else if (i < OFF_GFH) { src = Gs;   rem = i - OFF_GSH; Kd = 128; C = 384; mode = 1; }
        else if (i < OFF_GSL) { src = Gf;   rem = i - OFF_GFH; Kd = 128; C = 384; mode = 1; }
        else if (i < OFF_GFL) { src = Gs;   rem = i - OFF_GSL; Kd = 128; C = 384; mode = 2; }
        else                  { src = Gf;   rem = i - OFF_GFL; Kd = 128; C = 384; mode = 2; }
        int n = rem / (Kd * C);
        int r2 = rem % (Kd * C);
        int c = r2 / Kd;
        int k = r2 % Kd;
        size_t si = (size_t)n * Kd * C + (size_t)k * C + c;
        float v = ldx(isb, src, si);
        ushortT o;
        if (mode == 2) {
            bf16 h = __float2bfloat16(v);
            o = f2b(v - __bfloat162float(h));   // lo residue (0 when src is bf16)
        } else {
            o = f2b(v);
        }
        wt[i] = o;
    }
}

// nodes -> nlist (bucketed; padding masked positionally by ncnt downstream).
// Also computes and publishes eoff/noff (absorbs scan_offsets).
__global__ void fill_bins(const int* __restrict__ gate, const int* __restrict__ lev, int N,
                          const int* __restrict__ ecnt, const int* __restrict__ ncnt,
                          int* __restrict__ eoff, int* __restrict__ noff,
                          int* __restrict__ ncur, int* __restrict__ nlist) {
    __shared__ int s_noff[21], s_eoff[21];
    __shared__ int nc[20], nb[20];
    int tid = threadIdx.x;
    if (tid == 0) {
        int o = 0;
        for (int b = 0; b < 20; ++b) { s_noff[b] = o; o += ((ncnt[b] + TN - 1) / TN) * TN; }
        s_noff[20] = o;
        o = 0;
        for (int b = 0; b < 20; ++b) { s_eoff[b] = o; o += ((ecnt[b] + TE - 1) / TE) * TE; }
        s_eoff[20] = o;
    }
    if (tid < 20) nc[tid] = 0;
    __syncthreads();
    if (blockIdx.x == 0 && tid < 21) {
        noff[tid] = s_noff[tid];
        eoff[tid] = s_eoff[tid];
    }
    int i = blockIdx.x * blockDim.x + tid;
    int bn = -1, rn = 0;
    if (i < N) {
        int l = lev[i];
        if (l >= 1 && l < NLEV && gate[i] >= 1) { bn = (l - 1) * 5 + TMAP[gate[i]]; rn = atomicAdd(&nc[bn], 1); }
    }
    __syncthreads();
    if (tid < 20) nb[tid] = nc[tid] ? atomicAdd(&ncur[tid], nc[tid]) : 0;
    __syncthreads();
    if (bn >= 0) nlist[s_noff[bn] + nb[bn] + rn] = i;
}

// ===== finish_buckets (20 blocks): per-bucket degree prefix-scan -> nodeoff,
// then scatter this bucket's edges dst-contiguously into elist =====
__global__ __launch_bounds__(256) void finish_buckets(
    const int* __restrict__ nlist, const int* __restrict__ noff,
    const int* __restrict__ ncnt, const int* __restrict__ eoff,
    const int* __restrict__ ndeg, int* __restrict__ nodeoff,
    const int* __restrict__ dstA, const int* __restrict__ lev,
    const int* __restrict__ gate, int E,
    int* __restrict__ ecur_n, int* __restrict__ elist) {
    int b = blockIdx.x;  // 0..19
    int start = noff[b];
    int cnt = ncnt[b];
    int ebase = eoff[b];
    __shared__ int sc[256];
    int tid = threadIdx.x;
    int carry = 0;
    for (int chunk = 0; chunk < cnt; chunk += 256) {
        __syncthreads();
        int i = chunk + tid;
        int v = -1, dg = 0;
        if (i < cnt) { v = nlist[start + i]; dg = ndeg[v]; }
        sc[tid] = dg;
        __syncthreads();
        for (int off = 1; off < 256; off <<= 1) {
            int y = (tid >= off) ? sc[tid - off] : 0;
            __syncthreads();
            sc[tid] += y;
            __syncthreads();
        }
        if (v >= 0) nodeoff[v] = ebase + carry + (sc[tid] - dg);
        carry += sc[255];
    }
    __threadfence_block();
    __syncthreads();
    // Phase B: this bucket's edges
    int blev = b / 5 + 1, bt = b % 5;
    for (int i = tid; i < E; i += 256) {
        int d = dstA[i];
        if (lev[d] != blev) continue;
        if (TMAP[gate[d]] != bt) continue;
        int pos = nodeoff[d] + atomicAdd(&ecur_n[d], 1);
        elist[pos] = i;
    }
}

// ================= MFMA edge pass (grid-stride; dst-grouped tiles; LDS pre-reduced atomics) =================
__global__ __launch_bounds__(256) void edge_mfma(
    const ushortT* __restrict__ hsb, const ushortT* __restrict__ hfb,
    const ushortT* __restrict__ wt,
    const void* __restrict__ bs1, const void* __restrict__ bs2,
    const void* __restrict__ bf1, const void* __restrict__ bf2,
    const void* __restrict__ bnf1, const void* __restrict__ bnf2,
    const int* __restrict__ dstA, const int* __restrict__ srcA,
    const int* __restrict__ gate,
    const int* __restrict__ eoff, const int* __restrict__ ecnt,
    const int* __restrict__ elist,
    float* __restrict__ agg_s, float* __restrict__ agg_f, int level) {
    int lvl = (level - 1) * 5;
    int lo = eoff[lvl];
    int nt = (eoff[lvl + 5] - lo) / TE;

    __shared__ int se[TE], de[TE];
    __shared__ bf16 hid[2][16][136];      // 272B rows: 16B-aligned
    __shared__ float emsg[2][16][128];    // per-edge messages (+bias) for pre-reduction

    int tid = threadIdx.x;
    int wv = tid >> 6, pass = wv >> 1, hc = wv & 1, l = tid & 63;
    int lg = l >> 4, lr = l & 15;
    int isb = g_flag;

    for (int ti = blockIdx.x; ti < nt; ti += gridDim.x) {
        int base = lo + ti * TE;
        int b = 0;
#pragma unroll
        for (int bb = 1; bb < 5; ++bb) if (base >= eoff[lvl + bb]) b = bb;
        int nvalid = eoff[lvl + b] + ecnt[lvl + b] - base;
        if (nvalid <= 0) continue;       // block-uniform
        if (nvalid > TE) nvalid = TE;

        int c = gate[dstA[elist[base]]];   // uniform over tile
        int t = TMAP[c], fi = FMAP[c];

        if (tid < TE) {
            if (tid < nvalid) {
                int e = elist[base + tid];
                se[tid] = srcA[e];
                de[tid] = dstA[e];
            } else {
                se[tid] = -1;
                de[tid] = -1;
            }
        }
        __syncthreads();

        int src = se[lr];   // A-operand row owned by this lane

        // ---- layer 1 ----
        int KS1; size_t wb1; int K1;
        if (pass == 0)      { KS1 = 4; wb1 = OFF_S1 + (size_t)t * 16384; K1 = 128; }
        else if (c == 2)    { KS1 = 4; wb1 = OFF_NF1; K1 = 128; }
        else                { KS1 = 8; wb1 = OFF_F1 + (size_t)fi * 32768; K1 = 256; }

        f32x4 a0 = {0.f,0.f,0.f,0.f}, a1 = a0, a2 = a0, a3 = a0;
        for (int ks = 0; ks < KS1; ++ks) {
            bf16x8 a = {0,0,0,0,0,0,0,0};
            if (src >= 0) {
                int kk = ks * 32 + lg * 8;
                const ushortT* ap;
                if (pass == 0)      ap = hsb + (size_t)src * D + kk;
                else if (c == 2)    ap = hfb + (size_t)src * D + kk;
                else                ap = (kk < 128) ? (hsb + (size_t)src * D + kk)
                                                    : (hfb + (size_t)src * D + (kk - 128));
                a = *(const bf16x8*)ap;
            }
            int kb = ks * 32 + lg * 8;
            {
                bf16x8 b2 = *(const bf16x8*)&wt[wb1 + (size_t)(hc * 64 + 0 * 16 + lr) * K1 + kb];
                a0 = __builtin_amdgcn_mfma_f32_16x16x32_bf16(a, b2, a0, 0, 0, 0);
            }
            {
                bf16x8 b2 = *(const bf16x8*)&wt[wb1 + (size_t)(hc * 64 + 1 * 16 + lr) * K1 + kb];
                a1 = __builtin_amdgcn_mfma_f32_16x16x32_bf16(a, b2, a1, 0, 0, 0);
            }
            {
                bf16x8 b2 = *(const bf16x8*)&wt[wb1 + (size_t)(hc * 64 + 2 * 16 + lr) * K1 + kb];
                a2 = __builtin_amdgcn_mfma_f32_16x16x32_bf16(a, b2, a2, 0, 0, 0);
            }
            {
                bf16x8 b2 = *(const bf16x8*)&wt[wb1 + (size_t)(hc * 64 + 3 * 16 + lr) * K1 + kb];
                a3 = __builtin_amdgcn_mfma_f32_16x16x32_bf16(a, b2, a3, 0, 0, 0);
            }
        }

        // bias + relu -> bf16 hidden in LDS
        const void* b1p = (pass == 0) ? bs1 : (c == 2 ? bnf1 : bf1);
        size_t b1o = (pass == 0) ? (size_t)t * D : (c == 2 ? 0 : (size_t)fi * D);
        {
            f32x4 av[4] = { a0, a1, a2, a3 };
#pragma unroll
            for (int ct = 0; ct < 4; ++ct) {
                int cc = hc * 64 + ct * 16 + lr;
                float bb = ldx(isb, b1p, b1o + cc);
#pragma unroll
                for (int r = 0; r < 4; ++r) {
                    int m = lg * 4 + r;
                    float v = fmaxf(av[ct][r] + bb, 0.f);
                    hid[pass][m][cc] = __float2bfloat16(v);
                }
            }
        }
        __syncthreads();

        // ---- layer 2 (K=128 over hidden) ----
        size_t wb2 = (pass == 0) ? (OFF_S2 + (size_t)t * 16384)
                                 : (c == 2 ? (size_t)OFF_NF2 : (OFF_F2 + (size_t)fi * 16384));
        a0 = (f32x4){0.f,0.f,0.f,0.f}; a1 = a0; a2 = a0; a3 = a0;
#pragma unroll
        for (int ks = 0; ks < 4; ++ks) {
            bf16x8 a = *(const bf16x8*)&hid[pass][lr][ks * 32 + lg * 8];
            int kb = ks * 32 + lg * 8;
            {
                bf16x8 b2 = *(const bf16x8*)&wt[wb2 + (size_t)(hc * 64 + 0 * 16 + lr) * 128 + kb];
                a0 = __builtin_amdgcn_mfma_f32_16x16x32_bf16(a, b2, a0, 0, 0, 0);
            }
            {
                bf16x8 b2 = *(const bf16x8*)&wt[wb2 + (size_t)(hc * 64 + 1 * 16 + lr) * 128 + kb];
                a1 = __builtin_amdgcn_mfma_f32_16x16x32_bf16(a, b2, a1, 0, 0, 0);
            }
            {
                bf16x8 b2 = *(const bf16x8*)&wt[wb2 + (size_t)(hc * 64 + 2 * 16 + lr) * 128 + kb];
                a2 = __builtin_amdgcn_mfma_f32_16x16x32_bf16(a, b2, a2, 0, 0, 0);
            }
            {
                bf16x8 b2 = *(const bf16x8*)&wt[wb2 + (size_t)(hc * 64 + 3 * 16 + lr) * 128 + kb];
                a3 = __builtin_amdgcn_mfma_f32_16x16x32_bf16(a, b2, a3, 0, 0, 0);
            }
        }

        // per-edge bias folded in, stash to LDS for same-dst pre-reduction
        const void* b2p = (pass == 0) ? bs2 : (c == 2 ? bnf2 : bf2);
        size_t b2o = (pass == 0) ? (size_t)t * D : (c == 2 ? 0 : (size_t)fi * D);
        {
            f32x4 av[4] = { a0, a1, a2, a3 };
#pragma unroll
            for (int ct = 0; ct < 4; ++ct) {
                int cc = hc * 64 + ct * 16 + lr;
                float bb = ldx(isb, b2p, b2o + cc);
#pragma unroll
                for (int r = 0; r < 4; ++r) {
                    int m = lg * 4 + r;
                    emsg[pass][m][cc] = av[ct][r] + bb;
                }
            }
        }
        __syncthreads();

        // run-detect on de[] (dst-grouped): one atomic per distinct dst per col
        float* aggp = pass ? agg_f : agg_s;
        int col = hc * 64 + l;
        float s = 0.f;
        for (int m = 0; m < TE; ++m) {
            int d = de[m];
            if (d < 0) break;                 // padding is contiguous at tile end
            s += emsg[pass][m][col];
            bool flush = (m == TE - 1) || (de[m + 1] != d);
            if (flush) {
                atomicAdd(&aggp[(size_t)d * D + col], s);
                s = 0.f;
            }
        }
        __syncthreads();   // protect se/de/emsg before next grid-stride tile
    }
}

// ===== fused node GRU: MFMA gi (hi/lo compensated) -> LDS -> nonlinearity =====
// validity from ncnt (positional); epilogue writes FINAL output rows directly
template <int ISB>
__device__ void node_fused_body(
    const float* __restrict__ agg_s, const float* __restrict__ agg_f,
    const ushortT* __restrict__ wt,
    const void* __restrict__ Gs_bih, const void* __restrict__ Gs_bhh,
    const void* __restrict__ Gf_bih, const void* __restrict__ Gf_bhh,
    ushortT* __restrict__ hsb, ushortT* __restrict__ hfb,
    void* __restrict__ out, int ND,
    const int* __restrict__ gate,
    const int* __restrict__ noff, const int* __restrict__ ncnt,
    const int* __restrict__ nlist,
    int level, float (*gi)[3][16][128]) {
    int lvl = (level - 1) * 5;
    int lo = noff[lvl];
    int hi = noff[lvl + 5];
    int base = lo + blockIdx.x * TN;
    if (base >= hi) return;
    int b = 0;
#pragma unroll
    for (int bb = 1; bb < 5; ++bb) if (base >= noff[lvl + bb]) b = bb;
    int nvalid = noff[lvl + b] + ncnt[lvl + b] - base;
    if (nvalid <= 0) return;
    if (nvalid > TN) nvalid = TN;

    int tid = threadIdx.x;
    int w = tid >> 6, l = tid & 63;
    int lg = l >> 4, lr = l & 15;
    int p = w / 6, cg = w % 6;
    int t = TMAP[gate[nlist[base]]];

    const float* agg = p ? agg_f : agg_s;
    size_t wbh = (p ? OFF_GFH : OFF_GSH) + (size_t)t * 49152;
    size_t wbl = (p ? OFF_GFL : OFF_GSL) + (size_t)t * 49152;

    int v = (lr < nvalid) ? nlist[base + lr] : -1;   // A-operand row owned by this lane

    f32x4 acc[4];
#pragma unroll
    for (int q = 0; q < 4; ++q) acc[q] = (f32x4){0.f, 0.f, 0.f, 0.f};

    for (int ks = 0; ks < 4; ++ks) {
        bf16x8 ahi = {0,0,0,0,0,0,0,0}, alo = ahi;
        if (v >= 0) {
            const float* ap = agg + (size_t)v * D + ks * 32 + lg * 8;
            float4 f0 = *(const float4*)ap;
            float4 f1 = *(const float4*)(ap + 4);
            float av[8] = { f0.x, f0.y, f0.z, f0.w, f1.x, f1.y, f1.z, f1.w };
#pragma unroll
            for (int j = 0; j < 8; ++j) {
                bf16 h = __float2bfloat16(av[j]);
                ahi[j] = (short)*reinterpret_cast<ushortT*>(&h);
                float r = av[j] - __bfloat162float(h);
                bf16 l2 = __float2bfloat16(r);
                alo[j] = (short)*reinterpret_cast<ushortT*>(&l2);
            }
        }
        int kb = ks * 32 + lg * 8;
#pragma unroll
        for (int q = 0; q < 4; ++q) {
            int col = (cg * 4 + q) * 16 + lr;
            bf16x8 bh = *(const bf16x8*)&wt[wbh + (size_t)col * 128 + kb];
            acc[q] = __builtin_amdgcn_mfma_f32_16x16x32_bf16(ahi, bh, acc[q], 0, 0, 0);
            acc[q] = __builtin_amdgcn_mfma_f32_16x16x32_bf16(alo, bh, acc[q], 0, 0, 0);
            if (!ISB) {   // f32 weights: add hi*lo correction
                bf16x8 bl = *(const bf16x8*)&wt[wbl + (size_t)col * 128 + kb];
                acc[q] = __builtin_amdgcn_mfma_f32_16x16x32_bf16(ahi, bl, acc[q], 0, 0, 0);
            }
        }
    }

#pragma unroll
    for (int q = 0; q < 4; ++q) {
        int ct = cg * 4 + q;
        int g = ct >> 3, j = (ct & 7) * 16 + lr;
#pragma unroll
        for (int r = 0; r < 4; ++r) gi[p][g][lg * 4 + r][j] = acc[q][r];
    }
    __syncthreads();

    if (tid < 256) {
        int pp = tid >> 7, j = tid & 127;
        const void* bih = pp ? Gf_bih : Gs_bih;
        const void* bhh = pp ? Gf_bhh : Gs_bhh;
        float br = ld<ISB>(bih, (size_t)t * 384 + j);
        float bz = ld<ISB>(bih, (size_t)t * 384 + 128 + j);
        float bn = ld<ISB>(bih, (size_t)t * 384 + 256 + j);
        float hr = ld<ISB>(bhh, (size_t)t * 384 + j);
        float hz = ld<ISB>(bhh, (size_t)t * 384 + 128 + j);
        float hn = ld<ISB>(bhh, (size_t)t * 384 + 256 + j);
        ushortT* hb = pp ? hfb : hsb;
#pragma unroll
        for (int r = 0; r < TN; ++r) {
            if (r >= nvalid) break;
            int vv = nlist[base + r];
            float rr = sigm(gi[pp][0][r][j] + br + hr);
            float z = sigm(gi[pp][1][r][j] + bz + hz);
            float n = tanhf(gi[pp][2][r][j] + bn + rr * hn);
            float outv = (1.f - z) * n;
            size_t oidx = (size_t)pp * ND + (size_t)vv * D + j;
            if (ISB) ((ushortT*)out)[oidx] = f2b(outv);
            else     ((float*)out)[oidx] = outv;
            hb[(size_t)vv * D + j] = f2b(outv);
        }
    }
}

__global__ __launch_bounds__(768) void node_fused(
    const float* agg_s, const float* agg_f, const ushortT* wt,
    const void* Gs_bih, const void* Gs_bhh,
    const void* Gf_bih, const void* Gf_bhh,
    ushortT* hsb, ushortT* hfb, void* out, int ND,
    const int* gate, const int* noff, const int* ncnt, const int* nlist, int level) {
    __shared__ float gi[2][3][16][128];
    if (g_flag)
        node_fused_body<1>(agg_s, agg_f, wt, Gs_bih, Gs_bhh, Gf_bih, Gf_bhh,
                           hsb, hfb, out, ND, gate, noff, ncnt, nlist, level, gi);
    else
        node_fused_body<0>(agg_s, agg_f, wt, Gs_bih, Gs_bhh, Gf_bih, Gf_bhh,
                           hsb, hfb, out, ND, gate, noff, ncnt, nlist, level, gi);
}

extern "C" void kernel_launch(void* const* d_in, const int* in_sizes, int n_in,
                              void* d_out, int out_size, void* d_ws, size_t ws_size,
                              hipStream_t stream) {
    const void* hs_init = d_in[0];
    const void* Ws1 = d_in[1];
    const void* bs1 = d_in[2];
    const void* Ws2 = d_in[3];
    const void* bs2 = d_in[4];
    const void* Wf1 = d_in[5];
    const void* bf1 = d_in[6];
    const void* Wf2 = d_in[7];
    const void* bf2 = d_in[8];
    const void* Wnf1 = d_in[9];
    const void* bnf1 = d_in[10];
    const void* Wnf2 = d_in[11];
    const void* bnf2 = d_in[12];
    const void* Gs_wih = d_in[13];
    const void* Gs_bih = d_in[15];
    const void* Gs_bhh = d_in[16];
    const void* Gf_wih = d_in[17];
    const void* Gf_bih = d_in[19];
    const void* Gf_bhh = d_in[20];
    const int* edge_index = (const int*)d_in[21];
    const int* gate = (const int*)d_in[22];
    const int* lev = (const int*)d_in[23];

    int E = in_sizes[21] / 2;
    int N = in_sizes[22];
    int ND = N * D;
    int cap = ((N / NLEV + 5 * TN + 64) + TN - 1) / TN * TN;

    float* agg_s = (float*)d_ws;
    float* agg_f = agg_s + ND;
    ushortT* hsb = (ushortT*)(agg_f + ND);           // ND ushorts
    ushortT* hfb = hsb + ND;
    ushortT* wt = hfb + ND;                          // WT_TOTAL ushorts
    int* meta = (int*)(wt + WT_TOTAL);
    int* ecnt = meta;            // 20
    int* ncnt = ecnt + 20;       // 20
    int* ncur = ncnt + 20;       // 20
    int* eoff = ncur + 20;       // 21
    int* noff = eoff + 21;       // 21  (meta total 102; pad to 128)
    int* ndeg = meta + 128;      // N
    int* ecur_n = ndeg + N;      // N
    int* nodeoff = ecur_n + N;   // N
    int* elist = nodeoff + N;    // E + 20*TE
    int* nlist = elist + (E + 20 * TE);  // N + 20*TN

    const int* srcA = edge_index;
    const int* dstA = edge_index + E;

    // single memset: bucket counters + per-node degree/cursor arrays
    hipMemsetAsync(meta, 0, (size_t)(128 + 2 * N) * sizeof(int), stream);

    int mx = (E > N) ? E : N;
    int B_init = (N + 7) / 8;
    int B_cnt = (mx + 255) / 256;
    int B_prep = (WT_TOTAL + 255) / 256;
    setup_a<<<B_init + B_cnt + B_prep, 256, 0, stream>>>(
        hs_init, gate, dstA, lev, E, N, ND,
        hsb, hfb, d_out, agg_s, agg_f,
        ecnt, ncnt, ndeg,
        Ws1, Ws2, Wf1, Wf2, Wnf1, Wnf2, Gs_wih, Gf_wih,
        wt, B_init, B_cnt);

    fill_bins<<<(N + 255) / 256, 256, 0, stream>>>(gate, lev, N, ecnt, ncnt,
                                                   eoff, noff, ncur, nlist);
    finish_buckets<<<20, 256, 0, stream>>>(nlist, noff, ncnt, eoff, ndeg, nodeoff,
                                           dstA, lev, gate, E, ecur_n, elist);

    int gridNcap = cap / TN;
    for (int level = 1; level < NLEV; ++level) {
        edge_mfma<<<EGRID, 256, 0, stream>>>(hsb, hfb, wt,
                                             bs1, bs2, bf1, bf2, bnf1, bnf2,
                                             dstA, srcA, gate, eoff, ecnt, elist,
                                             agg_s, agg_f, level);
        node_fused<<<gridNcap, 768, 0, stream>>>(agg_s, agg_f, wt,
                                                 Gs_bih, Gs_bhh, Gf_bih, Gf_bhh,
                                                 hsb, hfb, d_out, ND,
                                                 gate, noff, ncnt, nlist, level);
    }
}

// Round 16
// 243.785 us; speedup vs baseline: 2.0234x; 2.0234x over previous
//
#include <hip/hip_runtime.h>
#include <hip/hip_bf16.h>

typedef __hip_bfloat16 bf16;
typedef unsigned short ushortT;
typedef unsigned int uintT;
typedef __attribute__((ext_vector_type(8))) short bf16x8;
typedef __attribute__((ext_vector_type(4))) float f32x4;

#define D 128
#define NLEV 5
#define TE 16  // edges per tile (MFMA M=16)
#define TN 16  // nodes per tile
#define EGRID 2048  // grid-stride edge kernel

// weight blob element offsets (bf16 elements), all stored transposed [C][K]
#define OFF_S1 0          // [5][128][128]
#define OFF_S2 81920      // [5][128][128]
#define OFF_F1 163840     // [4][128][256]
#define OFF_F2 294912     // [4][128][128]
#define OFF_NF1 360448    // [128][128]
#define OFF_NF2 376832    // [128][128]
#define OFF_GSH 393216    // [5][384][128] Gs_wih hi
#define OFF_GFH 638976    // [5][384][128] Gf_wih hi
#define OFF_GSL 884736    // [5][384][128] Gs_wih lo
#define OFF_GFL 1130496   // [5][384][128] Gf_wih lo
#define WT_TOTAL 1376256

// gate code -> t (enumerate index in CODES=[3,2,5,1,4]); index 0 unused
__constant__ int TMAP[6] = { -1, 3, 1, 0, 4, 2 };
// gate code -> func-aggregator index (FIDX={3:0,5:1,1:2,4:3}); codes 0,2 unused
__constant__ int FMAP[6] = { -1, 2, -1, 0, 3, 1 };

// dtype flag: 1 = float tensors stored as bf16, 0 = stored as float32
__device__ int g_flag;

__device__ __forceinline__ float sigm(float x) { return 1.0f / (1.0f + __expf(-x)); }

__device__ __forceinline__ ushortT f2b(float v) {
    bf16 h = __float2bfloat16(v);
    return *reinterpret_cast<ushortT*>(&h);
}

template <int ISB>
__device__ __forceinline__ float ld(const void* p, size_t i) {
    if (ISB) return __bfloat162float(((const bf16*)p)[i]);
    return ((const float*)p)[i];
}

__device__ __forceinline__ float ldx(int isb, const void* p, size_t i) {
    return isb ? __bfloat162float(((const bf16*)p)[i]) : ((const float*)p)[i];
}

// ===== fused setup: role-partitioned blocks =====
__global__ __launch_bounds__(256) void setup_a(
    const void* __restrict__ hs_init, const int* __restrict__ gate,
    const int* __restrict__ dstA, const int* __restrict__ lev,
    int E, int N, int ND,
    ushortT* __restrict__ hsb, ushortT* __restrict__ hfb, void* __restrict__ out,
    float* __restrict__ agg_s, float* __restrict__ agg_f,
    int* __restrict__ ecnt, int* __restrict__ ncnt, int* __restrict__ ndeg,
    const void* Ws1, const void* Ws2, const void* Wf1, const void* Wf2,
    const void* Wnf1, const void* Wnf2, const void* Gs, const void* Gf,
    ushortT* __restrict__ wt, int B_init, int B_cnt) {
    __shared__ int sfl;
    __shared__ int lc[40];
    int tid = threadIdx.x;
    int bid = blockIdx.x;

    if (tid < 64) {
        float x = __bfloat162float(((const bf16*)hs_init)[2 * tid]);
        float ax = fabsf(x);
        bool sane = (x == 0.0f) || (ax > 1e-4f && ax < 64.0f);
        unsigned long long m = __ballot(sane);
        if (tid == 0) sfl = (__popcll(m) >= 32) ? 1 : 0;
    }
    __syncthreads();
    int isb = sfl;
    if (bid == 0 && tid == 0) g_flag = isb;

    if (bid < B_init) {
        // ---- init role: 8 nodes/block; each thread handles 4 consecutive j ----
        int v = (bid << 3) | (tid >> 5);
        int j = (tid & 31) * 4;
        if (v < N) {
            size_t idx = (size_t)v * D + j;
            bool pi = (gate[v] == 0);
            if (isb) {
                uint2 bv = make_uint2(0u, 0u);
                if (pi) bv = *(const uint2*)((const ushortT*)hs_init + idx);
                *(uint2*)&hsb[idx] = bv;
                *(uint2*)&hfb[idx] = make_uint2(0u, 0u);
                *(uint2*)&((ushortT*)out)[idx] = bv;
                *(uint2*)&((ushortT*)out)[ND + idx] = make_uint2(0u, 0u);
            } else {
                float4 fv = make_float4(0.f, 0.f, 0.f, 0.f);
                if (pi) fv = *(const float4*)((const float*)hs_init + idx);
                ushortT b0 = f2b(fv.x), b1 = f2b(fv.y), b2 = f2b(fv.z), b3 = f2b(fv.w);
                *(uint2*)&hsb[idx] = make_uint2((uintT)b0 | ((uintT)b1 << 16),
                                                (uintT)b2 | ((uintT)b3 << 16));
                *(uint2*)&hfb[idx] = make_uint2(0u, 0u);
                *(float4*)&((float*)out)[idx] = fv;
                *(float4*)&((float*)out)[ND + idx] = make_float4(0.f, 0.f, 0.f, 0.f);
            }
            *(float4*)&agg_s[idx] = make_float4(0.f, 0.f, 0.f, 0.f);
            *(float4*)&agg_f[idx] = make_float4(0.f, 0.f, 0.f, 0.f);
        }
    } else if (bid < B_init + B_cnt) {
        // ---- count role ----
        if (tid < 40) lc[tid] = 0;
        __syncthreads();
        int i = (bid - B_init) * 256 + tid;
        if (i < E) {
            int d = dstA[i]; int l = lev[d];
            if (l >= 1 && l < NLEV) {
                atomicAdd(&lc[(l - 1) * 5 + TMAP[gate[d]]], 1);
                atomicAdd(&ndeg[d], 1);
            }
        }
        if (i < N) {
            int l = lev[i];
            if (l >= 1 && l < NLEV && gate[i] >= 1)
                atomicAdd(&lc[20 + (l - 1) * 5 + TMAP[gate[i]]], 1);
        }
        __syncthreads();
        if (tid < 20 && lc[tid]) atomicAdd(&ecnt[tid], lc[tid]);
        if (tid >= 20 && tid < 40 && lc[tid]) atomicAdd(&ncnt[tid - 20], lc[tid]);
    } else {
        // ---- weight-prep role ----
        int i = (bid - B_init - B_cnt) * 256 + tid;
        if (i >= WT_TOTAL) return;
        const void* src; int Kd, C, rem, mode = 0;  // 0: plain, 1: hi, 2: lo
        if (i < OFF_S2)       { src = Ws1;  rem = i;           Kd = 128; C = 128; }
        else if (i < OFF_F1)  { src = Ws2;  rem = i - OFF_S2;  Kd = 128; C = 128; }
        else if (i < OFF_F2)  { src = Wf1;  rem = i - OFF_F1;  Kd = 256; C = 128; }
        else if (i < OFF_NF1) { src = Wf2;  rem = i - OFF_F2;  Kd = 128; C = 128; }
        else if (i < OFF_NF2) { src = Wnf1; rem = i - OFF_NF1; Kd = 128; C = 128; }
        else if (i < OFF_GSH) { src = Wnf2; rem = i - OFF_NF2; Kd = 128; C = 128; }
        else if (i < OFF_GFH) { src = Gs;   rem = i - OFF_GSH; Kd = 128; C = 384; mode = 1; }
        else if (i < OFF_GSL) { src = Gf;   rem = i - OFF_GFH; Kd = 128; C = 384; mode = 1; }
        else if (i < OFF_GFL) { src = Gs;   rem = i - OFF_GSL; Kd = 128; C = 384; mode = 2; }
        else                  { src = Gf;   rem = i - OFF_GFL; Kd = 128; C = 384; mode = 2; }
        int n = rem / (Kd * C);
        int r2 = rem % (Kd * C);
        int c = r2 / Kd;
        int k = r2 % Kd;
        size_t si = (size_t)n * Kd * C + (size_t)k * C + c;
        float v = ldx(isb, src, si);
        ushortT o;
        if (mode == 2) {
            bf16 h = __float2bfloat16(v);
            o = f2b(v - __bfloat162float(h));   // lo residue (0 when src is bf16)
        } else {
            o = f2b(v);
        }
        wt[i] = o;
    }
}

// nodes -> nlist (bucketed; padding masked positionally by ncnt downstream).
// Also computes and publishes eoff/noff (absorbs scan_offsets).
__global__ void fill_bins(const int* __restrict__ gate, const int* __restrict__ lev, int N,
                          const int* __restrict__ ecnt, const int* __restrict__ ncnt,
                          int* __restrict__ eoff, int* __restrict__ noff,
                          int* __restrict__ ncur, int* __restrict__ nlist) {
    __shared__ int s_noff[21], s_eoff[21];
    __shared__ int nc[20], nb[20];
    int tid = threadIdx.x;
    if (tid == 0) {
        int o = 0;
        for (int b = 0; b < 20; ++b) { s_noff[b] = o; o += ((ncnt[b] + TN - 1) / TN) * TN; }
        s_noff[20] = o;
        o = 0;
        for (int b = 0; b < 20; ++b) { s_eoff[b] = o; o += ((ecnt[b] + TE - 1) / TE) * TE; }
        s_eoff[20] = o;
    }
    if (tid < 20) nc[tid] = 0;
    __syncthreads();
    if (blockIdx.x == 0 && tid < 21) {
        noff[tid] = s_noff[tid];
        eoff[tid] = s_eoff[tid];
    }
    int i = blockIdx.x * blockDim.x + tid;
    int bn = -1, rn = 0;
    if (i < N) {
        int l = lev[i];
        if (l >= 1 && l < NLEV && gate[i] >= 1) { bn = (l - 1) * 5 + TMAP[gate[i]]; rn = atomicAdd(&nc[bn], 1); }
    }
    __syncthreads();
    if (tid < 20) nb[tid] = nc[tid] ? atomicAdd(&ncur[tid], nc[tid]) : 0;
    __syncthreads();
    if (bn >= 0) nlist[s_noff[bn] + nb[bn] + rn] = i;
}

// per-bucket prefix-scan of node degrees -> nodeoff[v]
__global__ __launch_bounds__(256) void bucket_scan(
    const int* __restrict__ nlist, const int* __restrict__ noff,
    const int* __restrict__ ncnt, const int* __restrict__ eoff,
    const int* __restrict__ ndeg, int* __restrict__ nodeoff) {
    int b = blockIdx.x;  // 0..19
    int start = noff[b];
    int cnt = ncnt[b];
    int ebase = eoff[b];
    __shared__ int sc[256];
    int tid = threadIdx.x;
    int carry = 0;
    for (int chunk = 0; chunk < cnt; chunk += 256) {
        __syncthreads();
        int i = chunk + tid;
        int v = -1, dg = 0;
        if (i < cnt) { v = nlist[start + i]; dg = ndeg[v]; }
        sc[tid] = dg;
        __syncthreads();
        for (int off = 1; off < 256; off <<= 1) {
            int y = (tid >= off) ? sc[tid - off] : 0;
            __syncthreads();
            sc[tid] += y;
            __syncthreads();
        }
        if (v >= 0) nodeoff[v] = ebase + carry + (sc[tid] - dg);
        carry += sc[255];
    }
}

// edges -> elist, dst-contiguous (single pass over E)
__global__ void fill_edges(const int* __restrict__ dstA, const int* __restrict__ lev,
                           int E, const int* __restrict__ nodeoff,
                           int* __restrict__ ecur_n, int* __restrict__ elist) {
    int i = blockIdx.x * blockDim.x + threadIdx.x;
    if (i >= E) return;
    int d = dstA[i];
    int l = lev[d];
    if (l >= 1 && l < NLEV) {
        int pos = nodeoff[d] + atomicAdd(&ecur_n[d], 1);
        elist[pos] = i;
    }
}

// ================= MFMA edge pass (grid-stride; dst-grouped tiles; LDS pre-reduced atomics) =================
__global__ __launch_bounds__(256) void edge_mfma(
    const ushortT* __restrict__ hsb, const ushortT* __restrict__ hfb,
    const ushortT* __restrict__ wt,
    const void* __restrict__ bs1, const void* __restrict__ bs2,
    const void* __restrict__ bf1, const void* __restrict__ bf2,
    const void* __restrict__ bnf1, const void* __restrict__ bnf2,
    const int* __restrict__ dstA, const int* __restrict__ srcA,
    const int* __restrict__ gate,
    const int* __restrict__ eoff, const int* __restrict__ ecnt,
    const int* __restrict__ elist,
    float* __restrict__ agg_s, float* __restrict__ agg_f, int level) {
    int lvl = (level - 1) * 5;
    int lo = eoff[lvl];
    int nt = (eoff[lvl + 5] - lo) / TE;

    __shared__ int se[TE], de[TE];
    __shared__ bf16 hid[2][16][136];      // 272B rows: 16B-aligned
    __shared__ float emsg[2][16][128];    // per-edge messages (+bias) for pre-reduction

    int tid = threadIdx.x;
    int wv = tid >> 6, pass = wv >> 1, hc = wv & 1, l = tid & 63;
    int lg = l >> 4, lr = l & 15;
    int isb = g_flag;

    for (int ti = blockIdx.x; ti < nt; ti += gridDim.x) {
        int base = lo + ti * TE;
        int b = 0;
#pragma unroll
        for (int bb = 1; bb < 5; ++bb) if (base >= eoff[lvl + bb]) b = bb;
        int nvalid = eoff[lvl + b] + ecnt[lvl + b] - base;
        if (nvalid <= 0) continue;       // block-uniform
        if (nvalid > TE) nvalid = TE;

        int c = gate[dstA[elist[base]]];   // uniform over tile
        int t = TMAP[c], fi = FMAP[c];

        if (tid < TE) {
            if (tid < nvalid) {
                int e = elist[base + tid];
                se[tid] = srcA[e];
                de[tid] = dstA[e];
            } else {
                se[tid] = -1;
                de[tid] = -1;
            }
        }
        __syncthreads();

        int src = se[lr];   // A-operand row owned by this lane

        // ---- layer 1 ----
        int KS1; size_t wb1; int K1;
        if (pass == 0)      { KS1 = 4; wb1 = OFF_S1 + (size_t)t * 16384; K1 = 128; }
        else if (c == 2)    { KS1 = 4; wb1 = OFF_NF1; K1 = 128; }
        else                { KS1 = 8; wb1 = OFF_F1 + (size_t)fi * 32768; K1 = 256; }

        f32x4 a0 = {0.f,0.f,0.f,0.f}, a1 = a0, a2 = a0, a3 = a0;
        for (int ks = 0; ks < KS1; ++ks) {
            bf16x8 a = {0,0,0,0,0,0,0,0};
            if (src >= 0) {
                int kk = ks * 32 + lg * 8;
                const ushortT* ap;
                if (pass == 0)      ap = hsb + (size_t)src * D + kk;
                else if (c == 2)    ap = hfb + (size_t)src * D + kk;
                else                ap = (kk < 128) ? (hsb + (size_t)src * D + kk)
                                                    : (hfb + (size_t)src * D + (kk - 128));
                a = *(const bf16x8*)ap;
            }
            int kb = ks * 32 + lg * 8;
            {
                bf16x8 b2 = *(const bf16x8*)&wt[wb1 + (size_t)(hc * 64 + 0 * 16 + lr) * K1 + kb];
                a0 = __builtin_amdgcn_mfma_f32_16x16x32_bf16(a, b2, a0, 0, 0, 0);
            }
            {
                bf16x8 b2 = *(const bf16x8*)&wt[wb1 + (size_t)(hc * 64 + 1 * 16 + lr) * K1 + kb];
                a1 = __builtin_amdgcn_mfma_f32_16x16x32_bf16(a, b2, a1, 0, 0, 0);
            }
            {
                bf16x8 b2 = *(const bf16x8*)&wt[wb1 + (size_t)(hc * 64 + 2 * 16 + lr) * K1 + kb];
                a2 = __builtin_amdgcn_mfma_f32_16x16x32_bf16(a, b2, a2, 0, 0, 0);
            }
            {
                bf16x8 b2 = *(const bf16x8*)&wt[wb1 + (size_t)(hc * 64 + 3 * 16 + lr) * K1 + kb];
                a3 = __builtin_amdgcn_mfma_f32_16x16x32_bf16(a, b2, a3, 0, 0, 0);
            }
        }

        // bias + relu -> bf16 hidden in LDS
        const void* b1p = (pass == 0) ? bs1 : (c == 2 ? bnf1 : bf1);
        size_t b1o = (pass == 0) ? (size_t)t * D : (c == 2 ? 0 : (size_t)fi * D);
        {
            f32x4 av[4] = { a0, a1, a2, a3 };
#pragma unroll
            for (int ct = 0; ct < 4; ++ct) {
                int cc = hc * 64 + ct * 16 + lr;
                float bb = ldx(isb, b1p, b1o + cc);
#pragma unroll
                for (int r = 0; r < 4; ++r) {
                    int m = lg * 4 + r;
                    float v = fmaxf(av[ct][r] + bb, 0.f);
                    hid[pass][m][cc] = __float2bfloat16(v);
                }
            }
        }
        __syncthreads();

        // ---- layer 2 (K=128 over hidden) ----
        size_t wb2 = (pass == 0) ? (OFF_S2 + (size_t)t * 16384)
                                 : (c == 2 ? (size_t)OFF_NF2 : (OFF_F2 + (size_t)fi * 16384));
        a0 = (f32x4){0.f,0.f,0.f,0.f}; a1 = a0; a2 = a0; a3 = a0;
#pragma unroll
        for (int ks = 0; ks < 4; ++ks) {
            bf16x8 a = *(const bf16x8*)&hid[pass][lr][ks * 32 + lg * 8];
            int kb = ks * 32 + lg * 8;
            {
                bf16x8 b2 = *(const bf16x8*)&wt[wb2 + (size_t)(hc * 64 + 0 * 16 + lr) * 128 + kb];
                a0 = __builtin_amdgcn_mfma_f32_16x16x32_bf16(a, b2, a0, 0, 0, 0);
            }
            {
                bf16x8 b2 = *(const bf16x8*)&wt[wb2 + (size_t)(hc * 64 + 1 * 16 + lr) * 128 + kb];
                a1 = __builtin_amdgcn_mfma_f32_16x16x32_bf16(a, b2, a1, 0, 0, 0);
            }
            {
                bf16x8 b2 = *(const bf16x8*)&wt[wb2 + (size_t)(hc * 64 + 2 * 16 + lr) * 128 + kb];
                a2 = __builtin_amdgcn_mfma_f32_16x16x32_bf16(a, b2, a2, 0, 0, 0);
            }
            {
                bf16x8 b2 = *(const bf16x8*)&wt[wb2 + (size_t)(hc * 64 + 3 * 16 + lr) * 128 + kb];
                a3 = __builtin_amdgcn_mfma_f32_16x16x32_bf16(a, b2, a3, 0, 0, 0);
            }
        }

        // per-edge bias folded in, stash to LDS for same-dst pre-reduction
        const void* b2p = (pass == 0) ? bs2 : (c == 2 ? bnf2 : bf2);
        size_t b2o = (pass == 0) ? (size_t)t * D : (c == 2 ? 0 : (size_t)fi * D);
        {
            f32x4 av[4] = { a0, a1, a2, a3 };
#pragma unroll
            for (int ct = 0; ct < 4; ++ct) {
                int cc = hc * 64 + ct * 16 + lr;
                float bb = ldx(isb, b2p, b2o + cc);
#pragma unroll
                for (int r = 0; r < 4; ++r) {
                    int m = lg * 4 + r;
                    emsg[pass][m][cc] = av[ct][r] + bb;
                }
            }
        }
        __syncthreads();

        // run-detect on de[] (dst-grouped): one atomic per distinct dst per col
        float* aggp = pass ? agg_f : agg_s;
        int col = hc * 64 + l;
        float s = 0.f;
        for (int m = 0; m < TE; ++m) {
            int d = de[m];
            if (d < 0) break;                 // padding is contiguous at tile end
            s += emsg[pass][m][col];
            bool flush = (m == TE - 1) || (de[m + 1] != d);
            if (flush) {
                atomicAdd(&aggp[(size_t)d * D + col], s);
                s = 0.f;
            }
        }
        __syncthreads();   // protect se/de/emsg before next grid-stride tile
    }
}

// ===== fused node GRU: MFMA gi (hi/lo compensated) -> LDS -> nonlinearity =====
template <int ISB>
__device__ void node_fused_body(
    const float* __restrict__ agg_s, const float* __restrict__ agg_f,
    const ushortT* __restrict__ wt,
    const void* __restrict__ Gs_bih, const void* __restrict__ Gs_bhh,
    const void* __restrict__ Gf_bih, const void* __restrict__ Gf_bhh,
    ushortT* __restrict__ hsb, ushortT* __restrict__ hfb,
    void* __restrict__ out, int ND,
    const int* __restrict__ gate,
    const int* __restrict__ noff, const int* __restrict__ ncnt,
    const int* __restrict__ nlist,
    int level, float (*gi)[3][16][128]) {
    int lvl = (level - 1) * 5;
    int lo = noff[lvl];
    int hi = noff[lvl + 5];
    int base = lo + blockIdx.x * TN;
    if (base >= hi) return;
    int b = 0;
#pragma unroll
    for (int bb = 1; bb < 5; ++bb) if (base >= noff[lvl + bb]) b = bb;
    int nvalid = noff[lvl + b] + ncnt[lvl + b] - base;
    if (nvalid <= 0) return;
    if (nvalid > TN) nvalid = TN;

    int tid = threadIdx.x;
    int w = tid >> 6, l = tid & 63;
    int lg = l >> 4, lr = l & 15;
    int p = w / 6, cg = w % 6;
    int t = TMAP[gate[nlist[base]]];

    const float* agg = p ? agg_f : agg_s;
    size_t wbh = (p ? OFF_GFH : OFF_GSH) + (size_t)t * 49152;
    size_t wbl = (p ? OFF_GFL : OFF_GSL) + (size_t)t * 49152;

    int v = (lr < nvalid) ? nlist[base + lr] : -1;   // A-operand row owned by this lane

    f32x4 acc[4];
#pragma unroll
    for (int q = 0; q < 4; ++q) acc[q] = (f32x4){0.f, 0.f, 0.f, 0.f};

    for (int ks = 0; ks < 4; ++ks) {
        bf16x8 ahi = {0,0,0,0,0,0,0,0}, alo = ahi;
        if (v >= 0) {
            const float* ap = agg + (size_t)v * D + ks * 32 + lg * 8;
            float4 f0 = *(const float4*)ap;
            float4 f1 = *(const float4*)(ap + 4);
            float av[8] = { f0.x, f0.y, f0.z, f0.w, f1.x, f1.y, f1.z, f1.w };
#pragma unroll
            for (int j = 0; j < 8; ++j) {
                bf16 h = __float2bfloat16(av[j]);
                ahi[j] = (short)*reinterpret_cast<ushortT*>(&h);
                float r = av[j] - __bfloat162float(h);
                bf16 l2 = __float2bfloat16(r);
                alo[j] = (short)*reinterpret_cast<ushortT*>(&l2);
            }
        }
        int kb = ks * 32 + lg * 8;
#pragma unroll
        for (int q = 0; q < 4; ++q) {
            int col = (cg * 4 + q) * 16 + lr;
            bf16x8 bh = *(const bf16x8*)&wt[wbh + (size_t)col * 128 + kb];
            acc[q] = __builtin_amdgcn_mfma_f32_16x16x32_bf16(ahi, bh, acc[q], 0, 0, 0);
            acc[q] = __builtin_amdgcn_mfma_f32_16x16x32_bf16(alo, bh, acc[q], 0, 0, 0);
            if (!ISB) {   // f32 weights: add hi*lo correction
                bf16x8 bl = *(const bf16x8*)&wt[wbl + (size_t)col * 128 + kb];
                acc[q] = __builtin_amdgcn_mfma_f32_16x16x32_bf16(ahi, bl, acc[q], 0, 0, 0);
            }
        }
    }

#pragma unroll
    for (int q = 0; q < 4; ++q) {
        int ct = cg * 4 + q;
        int g = ct >> 3, j = (ct & 7) * 16 + lr;
#pragma unroll
        for (int r = 0; r < 4; ++r) gi[p][g][lg * 4 + r][j] = acc[q][r];
    }
    __syncthreads();

    if (tid < 256) {
        int pp = tid >> 7, j = tid & 127;
        const void* bih = pp ? Gf_bih : Gs_bih;
        const void* bhh = pp ? Gf_bhh : Gs_bhh;
        float br = ld<ISB>(bih, (size_t)t * 384 + j);
        float bz = ld<ISB>(bih, (size_t)t * 384 + 128 + j);
        float bn = ld<ISB>(bih, (size_t)t * 384 + 256 + j);
        float hr = ld<ISB>(bhh, (size_t)t * 384 + j);
        float hz = ld<ISB>(bhh, (size_t)t * 384 + 128 + j);
        float hn = ld<ISB>(bhh, (size_t)t * 384 + 256 + j);
        ushortT* hb = pp ? hfb : hsb;
#pragma unroll
        for (int r = 0; r < TN; ++r) {
            if (r >= nvalid) break;
            int vv = nlist[base + r];
            float rr = sigm(gi[pp][0][r][j] + br + hr);
            float z = sigm(gi[pp][1][r][j] + bz + hz);
            float n = tanhf(gi[pp][2][r][j] + bn + rr * hn);
            float outv = (1.f - z) * n;
            size_t oidx = (size_t)pp * ND + (size_t)vv * D + j;
            if (ISB) ((ushortT*)out)[oidx] = f2b(outv);
            else     ((float*)out)[oidx] = outv;
            hb[(size_t)vv * D + j] = f2b(outv);
        }
    }
}

__global__ __launch_bounds__(768) void node_fused(
    const float* agg_s, const float* agg_f, const ushortT* wt,
    const void* Gs_bih, const void* Gs_bhh,
    const void* Gf_bih, const void* Gf_bhh,
    ushortT* hsb, ushortT* hfb, void* out, int ND,
    const int* gate, const int* noff, const int* ncnt, const int* nlist, int level) {
    __shared__ float gi[2][3][16][128];
    if (g_flag)
        node_fused_body<1>(agg_s, agg_f, wt, Gs_bih, Gs_bhh, Gf_bih, Gf_bhh,
                           hsb, hfb, out, ND, gate, noff, ncnt, nlist, level, gi);
    else
        node_fused_body<0>(agg_s, agg_f, wt, Gs_bih, Gs_bhh, Gf_bih, Gf_bhh,
                           hsb, hfb, out, ND, gate, noff, ncnt, nlist, level, gi);
}

extern "C" void kernel_launch(void* const* d_in, const int* in_sizes, int n_in,
                              void* d_out, int out_size, void* d_ws, size_t ws_size,
                              hipStream_t stream) {
    const void* hs_init = d_in[0];
    const void* Ws1 = d_in[1];
    const void* bs1 = d_in[2];
    const void* Ws2 = d_in[3];
    const void* bs2 = d_in[4];
    const void* Wf1 = d_in[5];
    const void* bf1 = d_in[6];
    const void* Wf2 = d_in[7];
    const void* bf2 = d_in[8];
    const void* Wnf1 = d_in[9];
    const void* bnf1 = d_in[10];
    const void* Wnf2 = d_in[11];
    const void* bnf2 = d_in[12];
    const void* Gs_wih = d_in[13];
    const void* Gs_bih = d_in[15];
    const void* Gs_bhh = d_in[16];
    const void* Gf_wih = d_in[17];
    const void* Gf_bih = d_in[19];
    const void* Gf_bhh = d_in[20];
    const int* edge_index = (const int*)d_in[21];
    const int* gate = (const int*)d_in[22];
    const int* lev = (const int*)d_in[23];

    int E = in_sizes[21] / 2;
    int N = in_sizes[22];
    int ND = N * D;
    int cap = ((N / NLEV + 5 * TN + 64) + TN - 1) / TN * TN;

    float* agg_s = (float*)d_ws;
    float* agg_f = agg_s + ND;
    ushortT* hsb = (ushortT*)(agg_f + ND);           // ND ushorts
    ushortT* hfb = hsb + ND;
    ushortT* wt = hfb + ND;                          // WT_TOTAL ushorts
    int* meta = (int*)(wt + WT_TOTAL);
    int* ecnt = meta;            // 20
    int* ncnt = ecnt + 20;       // 20
    int* ncur = ncnt + 20;       // 20
    int* eoff = ncur + 20;       // 21
    int* noff = eoff + 21;       // 21  (meta total 102; pad to 128)
    int* ndeg = meta + 128;      // N
    int* ecur_n = ndeg + N;      // N
    int* nodeoff = ecur_n + N;   // N
    int* elist = nodeoff + N;    // E + 20*TE
    int* nlist = elist + (E + 20 * TE);  // N + 20*TN

    const int* srcA = edge_index;
    const int* dstA = edge_index + E;

    // single memset: bucket counters + per-node degree/cursor arrays
    hipMemsetAsync(meta, 0, (size_t)(128 + 2 * N) * sizeof(int), stream);

    int mx = (E > N) ? E : N;
    int B_init = (N + 7) / 8;
    int B_cnt = (mx + 255) / 256;
    int B_prep = (WT_TOTAL + 255) / 256;
    setup_a<<<B_init + B_cnt + B_prep, 256, 0, stream>>>(
        hs_init, gate, dstA, lev, E, N, ND,
        hsb, hfb, d_out, agg_s, agg_f,
        ecnt, ncnt, ndeg,
        Ws1, Ws2, Wf1, Wf2, Wnf1, Wnf2, Gs_wih, Gf_wih,
        wt, B_init, B_cnt);

    fill_bins<<<(N + 255) / 256, 256, 0, stream>>>(gate, lev, N, ecnt, ncnt,
                                                   eoff, noff, ncur, nlist);
    bucket_scan<<<20, 256, 0, stream>>>(nlist, noff, ncnt, eoff, ndeg, nodeoff);
    fill_edges<<<(E + 255) / 256, 256, 0, stream>>>(dstA, lev, E, nodeoff, ecur_n, elist);

    int gridNcap = cap / TN;
    for (int level = 1; level < NLEV; ++level) {
        edge_mfma<<<EGRID, 256, 0, stream>>>(hsb, hfb, wt,
                                             bs1, bs2, bf1, bf2, bnf1, bnf2,
                                             dstA, srcA, gate, eoff, ecnt, elist,
                                             agg_s, agg_f, level);
        node_fused<<<gridNcap, 768, 0, stream>>>(agg_s, agg_f, wt,
                                                 Gs_bih, Gs_bhh, Gf_bih, Gf_bhh,
                                                 hsb, hfb, d_out, ND,
                                                 gate, noff, ncnt, nlist, level);
    }
}

// Round 17
// 243.035 us; speedup vs baseline: 2.0297x; 1.0031x over previous
//
#include <hip/hip_runtime.h>
#include <hip/hip_bf16.h>

typedef __hip_bfloat16 bf16;
typedef unsigned short ushortT;
typedef unsigned int uintT;
typedef __attribute__((ext_vector_type(8))) short bf16x8;
typedef __attribute__((ext_vector_type(4))) float f32x4;

#define D 128
#define NLEV 5
#define TE 16  // edges per tile (MFMA M=16)
#define TN 16  // nodes per tile
#define EGRID 2048  // grid-stride edge kernel

// weight blob element offsets (bf16 elements), all stored transposed [C][K]
#define OFF_S1 0          // [5][128][128]
#define OFF_S2 81920      // [5][128][128]
#define OFF_F1 163840     // [4][128][256]
#define OFF_F2 294912     // [4][128][128]
#define OFF_NF1 360448    // [128][128]
#define OFF_NF2 376832    // [128][128]
#define OFF_GSH 393216    // [5][384][128] Gs_wih hi
#define OFF_GFH 638976    // [5][384][128] Gf_wih hi
#define OFF_GSL 884736    // [5][384][128] Gs_wih lo
#define OFF_GFL 1130496   // [5][384][128] Gf_wih lo
#define WT_TOTAL 1376256

// gate code -> t (enumerate index in CODES=[3,2,5,1,4]); index 0 unused
__constant__ int TMAP[6] = { -1, 3, 1, 0, 4, 2 };
// gate code -> func-aggregator index (FIDX={3:0,5:1,1:2,4:3}); codes 0,2 unused
__constant__ int FMAP[6] = { -1, 2, -1, 0, 3, 1 };

// dtype flag: 1 = float tensors stored as bf16, 0 = stored as float32
__device__ int g_flag;

__device__ __forceinline__ float sigm(float x) { return 1.0f / (1.0f + __expf(-x)); }

__device__ __forceinline__ ushortT f2b(float v) {
    bf16 h = __float2bfloat16(v);
    return *reinterpret_cast<ushortT*>(&h);
}

template <int ISB>
__device__ __forceinline__ float ld(const void* p, size_t i) {
    if (ISB) return __bfloat162float(((const bf16*)p)[i]);
    return ((const float*)p)[i];
}

__device__ __forceinline__ float ldx(int isb, const void* p, size_t i) {
    return isb ? __bfloat162float(((const bf16*)p)[i]) : ((const float*)p)[i];
}

// ===== custom zero kernel (replaces 41µs runtime fillBufferAligned for 160KB) =====
__global__ void zero_meta(int* __restrict__ p, int n) {
    int i = (blockIdx.x * blockDim.x + threadIdx.x) * 4;
    if (i + 3 < n) {
        *(int4*)(p + i) = make_int4(0, 0, 0, 0);
    } else {
        for (int k = i; k < n; ++k) p[k] = 0;
    }
}

// ===== fused setup: role-partitioned blocks =====
__global__ __launch_bounds__(256) void setup_a(
    const void* __restrict__ hs_init, const int* __restrict__ gate,
    const int* __restrict__ dstA, const int* __restrict__ lev,
    int E, int N, int ND,
    ushortT* __restrict__ hsb, ushortT* __restrict__ hfb, void* __restrict__ out,
    float* __restrict__ agg_s, float* __restrict__ agg_f,
    int* __restrict__ ecnt, int* __restrict__ ncnt, int* __restrict__ ndeg,
    const void* Ws1, const void* Ws2, const void* Wf1, const void* Wf2,
    const void* Wnf1, const void* Wnf2, const void* Gs, const void* Gf,
    ushortT* __restrict__ wt, int B_init, int B_cnt) {
    __shared__ int sfl;
    __shared__ int lc[40];
    int tid = threadIdx.x;
    int bid = blockIdx.x;

    if (tid < 64) {
        float x = __bfloat162float(((const bf16*)hs_init)[2 * tid]);
        float ax = fabsf(x);
        bool sane = (x == 0.0f) || (ax > 1e-4f && ax < 64.0f);
        unsigned long long m = __ballot(sane);
        if (tid == 0) sfl = (__popcll(m) >= 32) ? 1 : 0;
    }
    __syncthreads();
    int isb = sfl;
    if (bid == 0 && tid == 0) g_flag = isb;

    if (bid < B_init) {
        // ---- init role: 8 nodes/block; each thread handles 4 consecutive j ----
        int v = (bid << 3) | (tid >> 5);
        int j = (tid & 31) * 4;
        if (v < N) {
            size_t idx = (size_t)v * D + j;
            bool pi = (gate[v] == 0);
            if (isb) {
                uint2 bv = make_uint2(0u, 0u);
                if (pi) bv = *(const uint2*)((const ushortT*)hs_init + idx);
                *(uint2*)&hsb[idx] = bv;
                *(uint2*)&hfb[idx] = make_uint2(0u, 0u);
                *(uint2*)&((ushortT*)out)[idx] = bv;
                *(uint2*)&((ushortT*)out)[ND + idx] = make_uint2(0u, 0u);
            } else {
                float4 fv = make_float4(0.f, 0.f, 0.f, 0.f);
                if (pi) fv = *(const float4*)((const float*)hs_init + idx);
                ushortT b0 = f2b(fv.x), b1 = f2b(fv.y), b2 = f2b(fv.z), b3 = f2b(fv.w);
                *(uint2*)&hsb[idx] = make_uint2((uintT)b0 | ((uintT)b1 << 16),
                                                (uintT)b2 | ((uintT)b3 << 16));
                *(uint2*)&hfb[idx] = make_uint2(0u, 0u);
                *(float4*)&((float*)out)[idx] = fv;
                *(float4*)&((float*)out)[ND + idx] = make_float4(0.f, 0.f, 0.f, 0.f);
            }
            *(float4*)&agg_s[idx] = make_float4(0.f, 0.f, 0.f, 0.f);
            *(float4*)&agg_f[idx] = make_float4(0.f, 0.f, 0.f, 0.f);
        }
    } else if (bid < B_init + B_cnt) {
        // ---- count role ----
        if (tid < 40) lc[tid] = 0;
        __syncthreads();
        int i = (bid - B_init) * 256 + tid;
        if (i < E) {
            int d = dstA[i]; int l = lev[d];
            if (l >= 1 && l < NLEV) {
                atomicAdd(&lc[(l - 1) * 5 + TMAP[gate[d]]], 1);
                atomicAdd(&ndeg[d], 1);
            }
        }
        if (i < N) {
            int l = lev[i];
            if (l >= 1 && l < NLEV && gate[i] >= 1)
                atomicAdd(&lc[20 + (l - 1) * 5 + TMAP[gate[i]]], 1);
        }
        __syncthreads();
        if (tid < 20 && lc[tid]) atomicAdd(&ecnt[tid], lc[tid]);
        if (tid >= 20 && tid < 40 && lc[tid]) atomicAdd(&ncnt[tid - 20], lc[tid]);
    } else {
        // ---- weight-prep role ----
        int i = (bid - B_init - B_cnt) * 256 + tid;
        if (i >= WT_TOTAL) return;
        const void* src; int Kd, C, rem, mode = 0;  // 0: plain, 1: hi, 2: lo
        if (i < OFF_S2)       { src = Ws1;  rem = i;           Kd = 128; C = 128; }
        else if (i < OFF_F1)  { src = Ws2;  rem = i - OFF_S2;  Kd = 128; C = 128; }
        else if (i < OFF_F2)  { src = Wf1;  rem = i - OFF_F1;  Kd = 256; C = 128; }
        else if (i < OFF_NF1) { src = Wf2;  rem = i - OFF_F2;  Kd = 128; C = 128; }
        else if (i < OFF_NF2) { src = Wnf1; rem = i - OFF_NF1; Kd = 128; C = 128; }
        else if (i < OFF_GSH) { src = Wnf2; rem = i - OFF_NF2; Kd = 128; C = 128; }
        else if (i < OFF_GFH) { src = Gs;   rem = i - OFF_GSH; Kd = 128; C = 384; mode = 1; }
        else if (i < OFF_GSL) { src = Gf;   rem = i - OFF_GFH; Kd = 128; C = 384; mode = 1; }
        else if (i < OFF_GFL) { src = Gs;   rem = i - OFF_GSL; Kd = 128; C = 384; mode = 2; }
        else                  { src = Gf;   rem = i - OFF_GFL; Kd = 128; C = 384; mode = 2; }
        int n = rem / (Kd * C);
        int r2 = rem % (Kd * C);
        int c = r2 / Kd;
        int k = r2 % Kd;
        size_t si = (size_t)n * Kd * C + (size_t)k * C + c;
        float v = ldx(isb, src, si);
        ushortT o;
        if (mode == 2) {
            bf16 h = __float2bfloat16(v);
            o = f2b(v - __bfloat162float(h));   // lo residue (0 when src is bf16)
        } else {
            o = f2b(v);
        }
        wt[i] = o;
    }
}

// nodes -> nlist (bucketed; padding masked positionally by ncnt downstream).
// Also computes and publishes eoff/noff (absorbs scan_offsets).
__global__ void fill_bins(const int* __restrict__ gate, const int* __restrict__ lev, int N,
                          const int* __restrict__ ecnt, const int* __restrict__ ncnt,
                          int* __restrict__ eoff, int* __restrict__ noff,
                          int* __restrict__ ncur, int* __restrict__ nlist) {
    __shared__ int s_noff[21], s_eoff[21];
    __shared__ int nc[20], nb[20];
    int tid = threadIdx.x;
    if (tid == 0) {
        int o = 0;
        for (int b = 0; b < 20; ++b) { s_noff[b] = o; o += ((ncnt[b] + TN - 1) / TN) * TN; }
        s_noff[20] = o;
        o = 0;
        for (int b = 0; b < 20; ++b) { s_eoff[b] = o; o += ((ecnt[b] + TE - 1) / TE) * TE; }
        s_eoff[20] = o;
    }
    if (tid < 20) nc[tid] = 0;
    __syncthreads();
    if (blockIdx.x == 0 && tid < 21) {
        noff[tid] = s_noff[tid];
        eoff[tid] = s_eoff[tid];
    }
    int i = blockIdx.x * blockDim.x + tid;
    int bn = -1, rn = 0;
    if (i < N) {
        int l = lev[i];
        if (l >= 1 && l < NLEV && gate[i] >= 1) { bn = (l - 1) * 5 + TMAP[gate[i]]; rn = atomicAdd(&nc[bn], 1); }
    }
    __syncthreads();
    if (tid < 20) nb[tid] = nc[tid] ? atomicAdd(&ncur[tid], nc[tid]) : 0;
    __syncthreads();
    if (bn >= 0) nlist[s_noff[bn] + nb[bn] + rn] = i;
}

// per-bucket prefix-scan of node degrees -> nodeoff[v]
__global__ __launch_bounds__(256) void bucket_scan(
    const int* __restrict__ nlist, const int* __restrict__ noff,
    const int* __restrict__ ncnt, const int* __restrict__ eoff,
    const int* __restrict__ ndeg, int* __restrict__ nodeoff) {
    int b = blockIdx.x;  // 0..19
    int start = noff[b];
    int cnt = ncnt[b];
    int ebase = eoff[b];
    __shared__ int sc[256];
    int tid = threadIdx.x;
    int carry = 0;
    for (int chunk = 0; chunk < cnt; chunk += 256) {
        __syncthreads();
        int i = chunk + tid;
        int v = -1, dg = 0;
        if (i < cnt) { v = nlist[start + i]; dg = ndeg[v]; }
        sc[tid] = dg;
        __syncthreads();
        for (int off = 1; off < 256; off <<= 1) {
            int y = (tid >= off) ? sc[tid - off] : 0;
            __syncthreads();
            sc[tid] += y;
            __syncthreads();
        }
        if (v >= 0) nodeoff[v] = ebase + carry + (sc[tid] - dg);
        carry += sc[255];
    }
}

// edges -> elist, dst-contiguous (single pass over E)
__global__ void fill_edges(const int* __restrict__ dstA, const int* __restrict__ lev,
                           int E, const int* __restrict__ nodeoff,
                           int* __restrict__ ecur_n, int* __restrict__ elist) {
    int i = blockIdx.x * blockDim.x + threadIdx.x;
    if (i >= E) return;
    int d = dstA[i];
    int l = lev[d];
    if (l >= 1 && l < NLEV) {
        int pos = nodeoff[d] + atomicAdd(&ecur_n[d], 1);
        elist[pos] = i;
    }
}

// ================= MFMA edge pass (grid-stride; dst-grouped tiles; LDS pre-reduced atomics) =================
__global__ __launch_bounds__(256) void edge_mfma(
    const ushortT* __restrict__ hsb, const ushortT* __restrict__ hfb,
    const ushortT* __restrict__ wt,
    const void* __restrict__ bs1, const void* __restrict__ bs2,
    const void* __restrict__ bf1, const void* __restrict__ bf2,
    const void* __restrict__ bnf1, const void* __restrict__ bnf2,
    const int* __restrict__ dstA, const int* __restrict__ srcA,
    const int* __restrict__ gate,
    const int* __restrict__ eoff, const int* __restrict__ ecnt,
    const int* __restrict__ elist,
    float* __restrict__ agg_s, float* __restrict__ agg_f, int level) {
    int lvl = (level - 1) * 5;
    int lo = eoff[lvl];
    int nt = (eoff[lvl + 5] - lo) / TE;

    __shared__ int se[TE], de[TE];
    __shared__ bf16 hid[2][16][136];      // 272B rows: 16B-aligned
    __shared__ float emsg[2][16][128];    // per-edge messages (+bias) for pre-reduction

    int tid = threadIdx.x;
    int wv = tid >> 6, pass = wv >> 1, hc = wv & 1, l = tid & 63;
    int lg = l >> 4, lr = l & 15;
    int isb = g_flag;

    for (int ti = blockIdx.x; ti < nt; ti += gridDim.x) {
        int base = lo + ti * TE;
        int b = 0;
#pragma unroll
        for (int bb = 1; bb < 5; ++bb) if (base >= eoff[lvl + bb]) b = bb;
        int nvalid = eoff[lvl + b] + ecnt[lvl + b] - base;
        if (nvalid <= 0) continue;       // block-uniform
        if (nvalid > TE) nvalid = TE;

        int c = gate[dstA[elist[base]]];   // uniform over tile
        int t = TMAP[c], fi = FMAP[c];

        if (tid < TE) {
            if (tid < nvalid) {
                int e = elist[base + tid];
                se[tid] = srcA[e];
                de[tid] = dstA[e];
            } else {
                se[tid] = -1;
                de[tid] = -1;
            }
        }
        __syncthreads();

        int src = se[lr];   // A-operand row owned by this lane

        // ---- layer 1 ----
        int KS1; size_t wb1; int K1;
        if (pass == 0)      { KS1 = 4; wb1 = OFF_S1 + (size_t)t * 16384; K1 = 128; }
        else if (c == 2)    { KS1 = 4; wb1 = OFF_NF1; K1 = 128; }
        else                { KS1 = 8; wb1 = OFF_F1 + (size_t)fi * 32768; K1 = 256; }

        f32x4 a0 = {0.f,0.f,0.f,0.f}, a1 = a0, a2 = a0, a3 = a0;
        for (int ks = 0; ks < KS1; ++ks) {
            bf16x8 a = {0,0,0,0,0,0,0,0};
            if (src >= 0) {
                int kk = ks * 32 + lg * 8;
                const ushortT* ap;
                if (pass == 0)      ap = hsb + (size_t)src * D + kk;
                else if (c == 2)    ap = hfb + (size_t)src * D + kk;
                else                ap = (kk < 128) ? (hsb + (size_t)src * D + kk)
                                                    : (hfb + (size_t)src * D + (kk - 128));
                a = *(const bf16x8*)ap;
            }
            int kb = ks * 32 + lg * 8;
            {
                bf16x8 b2 = *(const bf16x8*)&wt[wb1 + (size_t)(hc * 64 + 0 * 16 + lr) * K1 + kb];
                a0 = __builtin_amdgcn_mfma_f32_16x16x32_bf16(a, b2, a0, 0, 0, 0);
            }
            {
                bf16x8 b2 = *(const bf16x8*)&wt[wb1 + (size_t)(hc * 64 + 1 * 16 + lr) * K1 + kb];
                a1 = __builtin_amdgcn_mfma_f32_16x16x32_bf16(a, b2, a1, 0, 0, 0);
            }
            {
                bf16x8 b2 = *(const bf16x8*)&wt[wb1 + (size_t)(hc * 64 + 2 * 16 + lr) * K1 + kb];
                a2 = __builtin_amdgcn_mfma_f32_16x16x32_bf16(a, b2, a2, 0, 0, 0);
            }
            {
                bf16x8 b2 = *(const bf16x8*)&wt[wb1 + (size_t)(hc * 64 + 3 * 16 + lr) * K1 + kb];
                a3 = __builtin_amdgcn_mfma_f32_16x16x32_bf16(a, b2, a3, 0, 0, 0);
            }
        }

        // bias + relu -> bf16 hidden in LDS
        const void* b1p = (pass == 0) ? bs1 : (c == 2 ? bnf1 : bf1);
        size_t b1o = (pass == 0) ? (size_t)t * D : (c == 2 ? 0 : (size_t)fi * D);
        {
            f32x4 av[4] = { a0, a1, a2, a3 };
#pragma unroll
            for (int ct = 0; ct < 4; ++ct) {
                int cc = hc * 64 + ct * 16 + lr;
                float bb = ldx(isb, b1p, b1o + cc);
#pragma unroll
                for (int r = 0; r < 4; ++r) {
                    int m = lg * 4 + r;
                    float v = fmaxf(av[ct][r] + bb, 0.f);
                    hid[pass][m][cc] = __float2bfloat16(v);
                }
            }
        }
        __syncthreads();

        // ---- layer 2 (K=128 over hidden) ----
        size_t wb2 = (pass == 0) ? (OFF_S2 + (size_t)t * 16384)
                                 : (c == 2 ? (size_t)OFF_NF2 : (OFF_F2 + (size_t)fi * 16384));
        a0 = (f32x4){0.f,0.f,0.f,0.f}; a1 = a0; a2 = a0; a3 = a0;
#pragma unroll
        for (int ks = 0; ks < 4; ++ks) {
            bf16x8 a = *(const bf16x8*)&hid[pass][lr][ks * 32 + lg * 8];
            int kb = ks * 32 + lg * 8;
            {
                bf16x8 b2 = *(const bf16x8*)&wt[wb2 + (size_t)(hc * 64 + 0 * 16 + lr) * 128 + kb];
                a0 = __builtin_amdgcn_mfma_f32_16x16x32_bf16(a, b2, a0, 0, 0, 0);
            }
            {
                bf16x8 b2 = *(const bf16x8*)&wt[wb2 + (size_t)(hc * 64 + 1 * 16 + lr) * 128 + kb];
                a1 = __builtin_amdgcn_mfma_f32_16x16x32_bf16(a, b2, a1, 0, 0, 0);
            }
            {
                bf16x8 b2 = *(const bf16x8*)&wt[wb2 + (size_t)(hc * 64 + 2 * 16 + lr) * 128 + kb];
                a2 = __builtin_amdgcn_mfma_f32_16x16x32_bf16(a, b2, a2, 0, 0, 0);
            }
            {
                bf16x8 b2 = *(const bf16x8*)&wt[wb2 + (size_t)(hc * 64 + 3 * 16 + lr) * 128 + kb];
                a3 = __builtin_amdgcn_mfma_f32_16x16x32_bf16(a, b2, a3, 0, 0, 0);
            }
        }

        // per-edge bias folded in, stash to LDS for same-dst pre-reduction
        const void* b2p = (pass == 0) ? bs2 : (c == 2 ? bnf2 : bf2);
        size_t b2o = (pass == 0) ? (size_t)t * D : (c == 2 ? 0 : (size_t)fi * D);
        {
            f32x4 av[4] = { a0, a1, a2, a3 };
#pragma unroll
            for (int ct = 0; ct < 4; ++ct) {
                int cc = hc * 64 + ct * 16 + lr;
                float bb = ldx(isb, b2p, b2o + cc);
#pragma unroll
                for (int r = 0; r < 4; ++r) {
                    int m = lg * 4 + r;
                    emsg[pass][m][cc] = av[ct][r] + bb;
                }
            }
        }
        __syncthreads();

        // run-detect on de[] (dst-grouped): one atomic per distinct dst per col
        float* aggp = pass ? agg_f : agg_s;
        int col = hc * 64 + l;
        float s = 0.f;
        for (int m = 0; m < TE; ++m) {
            int d = de[m];
            if (d < 0) break;                 // padding is contiguous at tile end
            s += emsg[pass][m][col];
            bool flush = (m == TE - 1) || (de[m + 1] != d);
            if (flush) {
                atomicAdd(&aggp[(size_t)d * D + col], s);
                s = 0.f;
            }
        }
        __syncthreads();   // protect se/de/emsg before next grid-stride tile
    }
}

// ===== fused node GRU: MFMA gi (hi/lo compensated) -> LDS -> nonlinearity =====
template <int ISB>
__device__ void node_fused_body(
    const float* __restrict__ agg_s, const float* __restrict__ agg_f,
    const ushortT* __restrict__ wt,
    const void* __restrict__ Gs_bih, const void* __restrict__ Gs_bhh,
    const void* __restrict__ Gf_bih, const void* __restrict__ Gf_bhh,
    ushortT* __restrict__ hsb, ushortT* __restrict__ hfb,
    void* __restrict__ out, int ND,
    const int* __restrict__ gate,
    const int* __restrict__ noff, const int* __restrict__ ncnt,
    const int* __restrict__ nlist,
    int level, float (*gi)[3][16][128]) {
    int lvl = (level - 1) * 5;
    int lo = noff[lvl];
    int hi = noff[lvl + 5];
    int base = lo + blockIdx.x * TN;
    if (base >= hi) return;
    int b = 0;
#pragma unroll
    for (int bb = 1; bb < 5; ++bb) if (base >= noff[lvl + bb]) b = bb;
    int nvalid = noff[lvl + b] + ncnt[lvl + b] - base;
    if (nvalid <= 0) return;
    if (nvalid > TN) nvalid = TN;

    int tid = threadIdx.x;
    int w = tid >> 6, l = tid & 63;
    int lg = l >> 4, lr = l & 15;
    int p = w / 6, cg = w % 6;
    int t = TMAP[gate[nlist[base]]];

    const float* agg = p ? agg_f : agg_s;
    size_t wbh = (p ? OFF_GFH : OFF_GSH) + (size_t)t * 49152;
    size_t wbl = (p ? OFF_GFL : OFF_GSL) + (size_t)t * 49152;

    int v = (lr < nvalid) ? nlist[base + lr] : -1;   // A-operand row owned by this lane

    f32x4 acc[4];
#pragma unroll
    for (int q = 0; q < 4; ++q) acc[q] = (f32x4){0.f, 0.f, 0.f, 0.f};

    for (int ks = 0; ks < 4; ++ks) {
        bf16x8 ahi = {0,0,0,0,0,0,0,0}, alo = ahi;
        if (v >= 0) {
            const float* ap = agg + (size_t)v * D + ks * 32 + lg * 8;
            float4 f0 = *(const float4*)ap;
            float4 f1 = *(const float4*)(ap + 4);
            float av[8] = { f0.x, f0.y, f0.z, f0.w, f1.x, f1.y, f1.z, f1.w };
#pragma unroll
            for (int j = 0; j < 8; ++j) {
                bf16 h = __float2bfloat16(av[j]);
                ahi[j] = (short)*reinterpret_cast<ushortT*>(&h);
                float r = av[j] - __bfloat162float(h);
                bf16 l2 = __float2bfloat16(r);
                alo[j] = (short)*reinterpret_cast<ushortT*>(&l2);
            }
        }
        int kb = ks * 32 + lg * 8;
#pragma unroll
        for (int q = 0; q < 4; ++q) {
            int col = (cg * 4 + q) * 16 + lr;
            bf16x8 bh = *(const bf16x8*)&wt[wbh + (size_t)col * 128 + kb];
            acc[q] = __builtin_amdgcn_mfma_f32_16x16x32_bf16(ahi, bh, acc[q], 0, 0, 0);
            acc[q] = __builtin_amdgcn_mfma_f32_16x16x32_bf16(alo, bh, acc[q], 0, 0, 0);
            if (!ISB) {   // f32 weights: add hi*lo correction
                bf16x8 bl = *(const bf16x8*)&wt[wbl + (size_t)col * 128 + kb];
                acc[q] = __builtin_amdgcn_mfma_f32_16x16x32_bf16(ahi, bl, acc[q], 0, 0, 0);
            }
        }
    }

#pragma unroll
    for (int q = 0; q < 4; ++q) {
        int ct = cg * 4 + q;
        int g = ct >> 3, j = (ct & 7) * 16 + lr;
#pragma unroll
        for (int r = 0; r < 4; ++r) gi[p][g][lg * 4 + r][j] = acc[q][r];
    }
    __syncthreads();

    if (tid < 256) {
        int pp = tid >> 7, j = tid & 127;
        const void* bih = pp ? Gf_bih : Gs_bih;
        const void* bhh = pp ? Gf_bhh : Gs_bhh;
        float br = ld<ISB>(bih, (size_t)t * 384 + j);
        float bz = ld<ISB>(bih, (size_t)t * 384 + 128 + j);
        float bn = ld<ISB>(bih, (size_t)t * 384 + 256 + j);
        float hr = ld<ISB>(bhh, (size_t)t * 384 + j);
        float hz = ld<ISB>(bhh, (size_t)t * 384 + 128 + j);
        float hn = ld<ISB>(bhh, (size_t)t * 384 + 256 + j);
        ushortT* hb = pp ? hfb : hsb;
#pragma unroll
        for (int r = 0; r < TN; ++r) {
            if (r >= nvalid) break;
            int vv = nlist[base + r];
            float rr = sigm(gi[pp][0][r][j] + br + hr);
            float z = sigm(gi[pp][1][r][j] + bz + hz);
            float n = tanhf(gi[pp][2][r][j] + bn + rr * hn);
            float outv = (1.f - z) * n;
            size_t oidx = (size_t)pp * ND + (size_t)vv * D + j;
            if (ISB) ((ushortT*)out)[oidx] = f2b(outv);
            else     ((float*)out)[oidx] = outv;
            hb[(size_t)vv * D + j] = f2b(outv);
        }
    }
}

__global__ __launch_bounds__(768) void node_fused(
    const float* agg_s, const float* agg_f, const ushortT* wt,
    const void* Gs_bih, const void* Gs_bhh,
    const void* Gf_bih, const void* Gf_bhh,
    ushortT* hsb, ushortT* hfb, void* out, int ND,
    const int* gate, const int* noff, const int* ncnt, const int* nlist, int level) {
    __shared__ float gi[2][3][16][128];
    if (g_flag)
        node_fused_body<1>(agg_s, agg_f, wt, Gs_bih, Gs_bhh, Gf_bih, Gf_bhh,
                           hsb, hfb, out, ND, gate, noff, ncnt, nlist, level, gi);
    else
        node_fused_body<0>(agg_s, agg_f, wt, Gs_bih, Gs_bhh, Gf_bih, Gf_bhh,
                           hsb, hfb, out, ND, gate, noff, ncnt, nlist, level, gi);
}

extern "C" void kernel_launch(void* const* d_in, const int* in_sizes, int n_in,
                              void* d_out, int out_size, void* d_ws, size_t ws_size,
                              hipStream_t stream) {
    const void* hs_init = d_in[0];
    const void* Ws1 = d_in[1];
    const void* bs1 = d_in[2];
    const void* Ws2 = d_in[3];
    const void* bs2 = d_in[4];
    const void* Wf1 = d_in[5];
    const void* bf1 = d_in[6];
    const void* Wf2 = d_in[7];
    const void* bf2 = d_in[8];
    const void* Wnf1 = d_in[9];
    const void* bnf1 = d_in[10];
    const void* Wnf2 = d_in[11];
    const void* bnf2 = d_in[12];
    const void* Gs_wih = d_in[13];
    const void* Gs_bih = d_in[15];
    const void* Gs_bhh = d_in[16];
    const void* Gf_wih = d_in[17];
    const void* Gf_bih = d_in[19];
    const void* Gf_bhh = d_in[20];
    const int* edge_index = (const int*)d_in[21];
    const int* gate = (const int*)d_in[22];
    const int* lev = (const int*)d_in[23];

    int E = in_sizes[21] / 2;
    int N = in_sizes[22];
    int ND = N * D;
    int cap = ((N / NLEV + 5 * TN + 64) + TN - 1) / TN * TN;

    float* agg_s = (float*)d_ws;
    float* agg_f = agg_s + ND;
    ushortT* hsb = (ushortT*)(agg_f + ND);           // ND ushorts
    ushortT* hfb = hsb + ND;
    ushortT* wt = hfb + ND;                          // WT_TOTAL ushorts
    int* meta = (int*)(wt + WT_TOTAL);
    int* ecnt = meta;            // 20
    int* ncnt = ecnt + 20;       // 20
    int* ncur = ncnt + 20;       // 20
    int* eoff = ncur + 20;       // 21
    int* noff = eoff + 21;       // 21  (meta total 102; pad to 128)
    int* ndeg = meta + 128;      // N
    int* ecur_n = ndeg + N;      // N
    int* nodeoff = ecur_n + N;   // N
    int* elist = nodeoff + N;    // E + 20*TE
    int* nlist = elist + (E + 20 * TE);  // N + 20*TN

    const int* srcA = edge_index;
    const int* dstA = edge_index + E;

    // custom zero of meta+ndeg+ecur_n (runtime fill kernel measured 41us for this)
    int zn = 128 + 2 * N;
    zero_meta<<<(zn / 4 + 255) / 256, 256, 0, stream>>>(meta, zn);

    int mx = (E > N) ? E : N;
    int B_init = (N + 7) / 8;
    int B_cnt = (mx + 255) / 256;
    int B_prep = (WT_TOTAL + 255) / 256;
    setup_a<<<B_init + B_cnt + B_prep, 256, 0, stream>>>(
        hs_init, gate, dstA, lev, E, N, ND,
        hsb, hfb, d_out, agg_s, agg_f,
        ecnt, ncnt, ndeg,
        Ws1, Ws2, Wf1, Wf2, Wnf1, Wnf2, Gs_wih, Gf_wih,
        wt, B_init, B_cnt);

    fill_bins<<<(N + 255) / 256, 256, 0, stream>>>(gate, lev, N, ecnt, ncnt,
                                                   eoff, noff, ncur, nlist);
    bucket_scan<<<20, 256, 0, stream>>>(nlist, noff, ncnt, eoff, ndeg, nodeoff);
    fill_edges<<<(E + 255) / 256, 256, 0, stream>>>(dstA, lev, E, nodeoff, ecur_n, elist);

    int gridNcap = cap / TN;
    for (int level = 1; level < NLEV; ++level) {
        edge_mfma<<<EGRID, 256, 0, stream>>>(hsb, hfb, wt,
                                             bs1, bs2, bf1, bf2, bnf1, bnf2,
                                             dstA, srcA, gate, eoff, ecnt, elist,
                                             agg_s, agg_f, level);
        node_fused<<<gridNcap, 768, 0, stream>>>(agg_s, agg_f, wt,
                                                 Gs_bih, Gs_bhh, Gf_bih, Gf_bhh,
                                                 hsb, hfb, d_out, ND,
                                                 gate, noff, ncnt, nlist, level);
    }
}